// Round 7
// baseline (2425.690 us; speedup 1.0000x reference)
//
#include <hip/hip_runtime.h>
#include <math.h>

// Problem constants (N=80000, Rr=5, A=8, D=32, T=32, K=8 rotations, ROT_DELTA=1)
#define RR 5
#define AA 8
#define DD 32
#define TT 32
#define KK 8

#define RT2 0.70710678118654752f

typedef float v2f __attribute__((ext_vector_type(2)));
typedef float v4f __attribute__((ext_vector_type(4)));

static __device__ __forceinline__ v2f pkfma(v2f a, v2f b, v2f c) {
#if __has_builtin(__builtin_elementwise_fma)
    return __builtin_elementwise_fma(a, b, c);
#else
    v2f r; r.x = fmaf(a.x, b.x, c.x); r.y = fmaf(a.y, b.y, c.y); return r;
#endif
}
static __device__ __forceinline__ v4f pkfma4(v4f a, v4f b, v4f c) {
#if __has_builtin(__builtin_elementwise_fma)
    return __builtin_elementwise_fma(a, b, c);
#else
    v4f r; r.x = fmaf(a.x, b.x, c.x); r.y = fmaf(a.y, b.y, c.y);
    r.z = fmaf(a.z, b.z, c.z); r.w = fmaf(a.w, b.w, c.w); return r;
#endif
}

// ---------------------------------------------------------------------------
// W spectral precompute. Layout for the kernel's staged LDS slices:
//   Ws[(((r*2+h)*2+sub)*2+fh)*1024 + dl*128 + t*4 + f']
// where d = h*16 + sub*8 + dl, f = fh*4+f',
// f-pack = [F0,F4,R1,I1 | R2,I2,R3,I3].  One thread per (t,r,d) = 5120.
// ---------------------------------------------------------------------------
__global__ void wdft_kernel(const float* __restrict__ W, float* __restrict__ Ws) {
    int idx = blockIdx.x * 256 + threadIdx.x;
    if (idx >= TT * RR * DD) return;
    int d = idx & 31;
    int tr = idx >> 5;      // t*5+r
    int t = tr / 5;
    int r = tr - t * 5;
    float xa[8];
    #pragma unroll
    for (int a = 0; a < 8; ++a) xa[a] = W[(tr * 8 + a) * 32 + d];
    float s0 = xa[0] + xa[4], d0 = xa[0] - xa[4];
    float s1 = xa[1] + xa[5], d1 = xa[1] - xa[5];
    float s2 = xa[2] + xa[6], d2 = xa[2] - xa[6];
    float s3 = xa[3] + xa[7], d3 = xa[3] - xa[7];
    float s02 = s0 + s2, s13 = s1 + s3;
    float F0 = s02 + s13, F4 = s02 - s13;
    float R2 = s0 - s2, I2 = s3 - s1;
    float u = RT2 * (d1 - d3), v = RT2 * (d1 + d3);
    float R1 = d0 + u, R3 = d0 - u;
    float I1 = -d2 - v, I3 = d2 - v;
    int h = d >> 4;
    int sub = (d >> 3) & 1;
    int dl = d & 7;
    float* o0 = &Ws[(size_t)(((r * 2 + h) * 2 + sub) * 2 + 0) * 1024 + dl * 128 + t * 4];
    float* o1 = o0 + 1024;
    o0[0] = F0; o0[1] = F4; o0[2] = R1; o0[3] = I1;
    o1[0] = R2; o1[1] = I2; o1[2] = R3; o1[3] = I3;
}

// ---------------------------------------------------------------------------
// Fused kernel: gather + barycentric interp + forward DFT8 + spectral GEMM
// (vs conj(W-spectrum)) + IDFT8 + bias + angular max pool.
//
// Block = 256 threads (4 waves), 128 v/block (N=80000 -> 625 blocks, exact).
// d processed in two 16-d halves per r (Is holds one half's spectra).
// GEMM lane tile = 4 v x 4 t (square): per d, 8 Is-b128 + 8 W-b128 feed
// 224 MAC -> 14 MAC/b128 (vs 9.3 last round; LDS pipe was the limiter).
// Wave wv owns v in [wv*32, wv*32+32): lane vg=lane&7, tile v = wv*32+vg+8*vv
// -> Is read stride (132 floats = 4 banks): CONFLICT-FREE.  tg=lane>>3,
// t = tg+8j; Wl layout [fh][dl][t*4] -> tg stride 4 banks: CONFLICT-FREE.
// Is layout [v][fh(2)][dloc(16)][4f], row stride 132.
// W staged per (r,h) in two 8-d substages (Wl 8 KB); LDS = 75,776 B,
// 2 blocks/CU.  Norm reduce is wave-local (shfl over tg bits 8/16/32).
// ---------------------------------------------------------------------------
__global__ __launch_bounds__(256, 2)
void fused_conv_kernel(const float* __restrict__ sig,
                       const int* __restrict__ bc_idx,
                       const float* __restrict__ bc_w,
                       const float* __restrict__ Wsg,
                       const float* __restrict__ bias,
                       float* __restrict__ s_out,
                       int N) {
    __shared__ float Is[128 * 132];  // 67,584 B
    __shared__ float Wl[2048];       //  8,192 B

    int tid = threadIdx.x;
    int vBase = blockIdx.x * 128;
    int lane = tid & 63;
    int wv = tid >> 6;

    // GEMM lane roles
    int vg = lane & 7;
    int tg = lane >> 3;              // 0..7

    // gather lane roles (v4f granularity: 4 d's per lane)
    int d4 = tid & 3;
    int g = tid >> 2;                // 0..63

    // spectral accumulators [vv][j]: A0=(C0,C4) A1=(R1,I1) A2=(R2,I2) A3=(R3,I3)
    v2f A0[4][4], A1[4][4], A2[4][4], A3[4][4];
    #pragma unroll
    for (int vv = 0; vv < 4; ++vv)
        #pragma unroll
        for (int j = 0; j < 4; ++j) {
            A0[vv][j] = (v2f){0.f, 0.f}; A1[vv][j] = (v2f){0.f, 0.f};
            A2[vv][j] = (v2f){0.f, 0.f}; A3[vv][j] = (v2f){0.f, 0.f};
        }

    for (int r = 0; r < RR; ++r) {
        for (int h = 0; h < 2; ++h) {
            __syncthreads();  // prev GEMM done reading Is & Wl

            // ---- stage Wl substage 0 (contiguous coalesced copy) ----
            {
                const float* src = Wsg + (size_t)((r * 2 + h) * 2 + 0) * 2048 + tid * 8;
                v4f a = *(const v4f*)src;
                v4f b = *(const v4f*)(src + 4);
                *(v4f*)&Wl[tid * 8] = a;
                *(v4f*)&Wl[tid * 8 + 4] = b;
            }

            // ---- gather + interp + forward DFT8 (this d-half) -> Is ----
            #pragma unroll
            for (int pass = 0; pass < 2; ++pass) {
                int vv = g + 64 * pass;          // 0..127
                int vgl = vBase + vv;
                int vgc = (vgl < N) ? vgl : (N - 1);
                int base = (vgc * 40 + r * 8) * 3;
                v4f xa[8];
                #pragma unroll
                for (int a = 0; a < 8; ++a) {
                    int i0 = bc_idx[base + a * 3 + 0];
                    int i1 = bc_idx[base + a * 3 + 1];
                    int i2 = bc_idx[base + a * 3 + 2];
                    float w0 = bc_w[base + a * 3 + 0];
                    float w1 = bc_w[base + a * 3 + 1];
                    float w2 = bc_w[base + a * 3 + 2];
                    v4f r0 = *(const v4f*)&sig[(size_t)i0 * 32 + h * 16 + d4 * 4];
                    v4f r1 = *(const v4f*)&sig[(size_t)i1 * 32 + h * 16 + d4 * 4];
                    v4f r2 = *(const v4f*)&sig[(size_t)i2 * 32 + h * 16 + d4 * 4];
                    v4f w0v = {w0, w0, w0, w0};
                    v4f w1v = {w1, w1, w1, w1};
                    v4f w2v = {w2, w2, w2, w2};
                    xa[a] = pkfma4(w2v, r2, pkfma4(w1v, r1, w0v * r0));
                }
                // DFT8 (4 d-channels packed)
                v4f s0 = xa[0] + xa[4], dd0 = xa[0] - xa[4];
                v4f s1 = xa[1] + xa[5], dd1 = xa[1] - xa[5];
                v4f s2 = xa[2] + xa[6], dd2 = xa[2] - xa[6];
                v4f s3 = xa[3] + xa[7], dd3 = xa[3] - xa[7];
                v4f s02 = s0 + s2, s13 = s1 + s3;
                v4f F0 = s02 + s13, F4 = s02 - s13;
                v4f R2 = s0 - s2, I2 = s3 - s1;
                v4f rt2v = {RT2, RT2, RT2, RT2};
                v4f u = rt2v * (dd1 - dd3), vvv = rt2v * (dd1 + dd3);
                v4f R1 = dd0 + u, R3 = dd0 - u;
                v4f I1 = -dd2 - vvv, I3 = dd2 - vvv;
                // transpose to per-d spectra, f-half-split: 8 x b128
                float* ob = &Is[vv * 132];
                #pragma unroll
                for (int c = 0; c < 4; ++c) {
                    int dloc = 4 * d4 + c;
                    *(v4f*)&ob[dloc * 4]      = (v4f){F0[c], F4[c], R1[c], I1[c]};
                    *(v4f*)&ob[64 + dloc * 4] = (v4f){R2[c], I2[c], R3[c], I3[c]};
                }
            }

            #pragma unroll
            for (int sub = 0; sub < 2; ++sub) {
                if (sub == 1) {
                    __syncthreads();  // GEMM sub0 done reading Wl
                    const float* src = Wsg + (size_t)((r * 2 + h) * 2 + 1) * 2048 + tid * 8;
                    v4f a = *(const v4f*)src;
                    v4f b = *(const v4f*)(src + 4);
                    *(v4f*)&Wl[tid * 8] = a;
                    *(v4f*)&Wl[tid * 8 + 4] = b;
                }
                __syncthreads();  // Is (+Wl) visible

                // ---- spectral GEMM: 8 d's of this substage ----
                #pragma unroll 2
                for (int dl = 0; dl < 8; ++dl) {
                    int dloc = sub * 8 + dl;
                    v4f p0[4], p1[4];
                    #pragma unroll
                    for (int vv = 0; vv < 4; ++vv) {
                        int vrow = wv * 32 + vg + vv * 8;
                        p0[vv] = *(const v4f*)&Is[vrow * 132 + dloc * 4];
                        p1[vv] = *(const v4f*)&Is[vrow * 132 + 64 + dloc * 4];
                    }
                    #pragma unroll
                    for (int j = 0; j < 4; ++j) {
                        v4f q0 = *(const v4f*)&Wl[dl * 128 + (tg + 8 * j) * 4];
                        v4f q1 = *(const v4f*)&Wl[1024 + dl * 128 + (tg + 8 * j) * 4];
                        v2f w2v = {q0.z, q0.z}, w3v = {q0.w, q0.w};
                        v2f w4v = {q1.x, q1.x}, w5v = {q1.y, q1.y};
                        v2f w6v = {q1.z, q1.z}, w7v = {q1.w, q1.w};
                        #pragma unroll
                        for (int vv = 0; vv < 4; ++vv) {
                            v2f x1 = p0[vv].zw;
                            v2f x1n = {p0[vv].w, -p0[vv].z};
                            v2f x2 = p1[vv].xy;
                            v2f x2n = {p1[vv].y, -p1[vv].x};
                            v2f x3 = p1[vv].zw;
                            v2f x3n = {p1[vv].w, -p1[vv].z};
                            A0[vv][j] = pkfma(p0[vv].xy, q0.xy, A0[vv][j]);
                            A1[vv][j] = pkfma(x1, w2v, A1[vv][j]);
                            A1[vv][j] = pkfma(x1n, w3v, A1[vv][j]);
                            A2[vv][j] = pkfma(x2, w4v, A2[vv][j]);
                            A2[vv][j] = pkfma(x2n, w5v, A2[vv][j]);
                            A3[vv][j] = pkfma(x3, w6v, A3[vv][j]);
                            A3[vv][j] = pkfma(x3n, w7v, A3[vv][j]);
                        }
                    }
                }
            }
        }
    }

    // ---- epilogue per vv: IDFT8 + bias, wave-local pool, store ----
    float bj[4];
    #pragma unroll
    for (int j = 0; j < 4; ++j) bj[j] = bias[tg + 8 * j];

    #pragma unroll
    for (int vv = 0; vv < 4; ++vv) {
        float outk[8][4];
        #pragma unroll
        for (int j = 0; j < 4; ++j) {
            float C0 = A0[vv][j].x, C4 = A0[vv][j].y;
            float R1 = A1[vv][j].x, I1 = A1[vv][j].y;
            float R2 = A2[vv][j].x, I2 = A2[vv][j].y;
            float R3 = A3[vv][j].x, I3 = A3[vv][j].y;
            float e = 0.125f * (C0 + C4), o = 0.125f * (C0 - C4);
            float p = 0.25f * (R1 + R3), q = 0.25f * R2, s = 0.25f * (I1 - I3);
            float a_ = 0.25f * RT2 * (R1 - R3);
            float b_ = 0.25f * RT2 * (I1 + I3);
            float c_ = 0.25f * I2;
            float bb = bj[j];
            outk[0][j] = e + p + q + bb;
            outk[1][j] = o + a_ - b_ - c_ + bb;
            outk[2][j] = e - s - q + bb;
            outk[3][j] = o - a_ - b_ + c_ + bb;
            outk[4][j] = e - p + q + bb;
            outk[5][j] = o - a_ + b_ - c_ + bb;
            outk[6][j] = e + s - q + bb;
            outk[7][j] = o + a_ + b_ + c_ + bb;
        }
        float norms[8];
        #pragma unroll
        for (int k = 0; k < 8; ++k) {
            float nl = 0.f;
            #pragma unroll
            for (int j = 0; j < 4; ++j)
                nl = fmaf(outk[k][j], outk[k][j], nl);
            nl += __shfl_xor(nl, 8);
            nl += __shfl_xor(nl, 16);
            nl += __shfl_xor(nl, 32);
            norms[k] = nl;
        }
        float best = -1.f;
        int bk = 0;
        #pragma unroll
        for (int k = 0; k < 8; ++k) {
            float n = sqrtf(norms[k]);
            if (n > best) { best = n; bk = k; }
        }
        int vOut = vBase + wv * 32 + vg + vv * 8;
        if (vOut < N) {
            float sel[4];
            #pragma unroll
            for (int j = 0; j < 4; ++j) sel[j] = 0.f;
            #pragma unroll
            for (int k = 0; k < 8; ++k) {
                if (k == bk) {
                    #pragma unroll
                    for (int j = 0; j < 4; ++j) sel[j] = outk[k][j];
                }
            }
            float* o = s_out + (size_t)vOut * 32 + tg;
            o[0]  = sel[0];
            o[8]  = sel[1];
            o[16] = sel[2];
            o[24] = sel[3];
        }
    }
}

// ---------------------------------------------------------------------------
// Stats: per-column (t) sum and sumsq over N rows, fp64 accumulation.
// ---------------------------------------------------------------------------
__global__ void stats_kernel(const float* __restrict__ s,
                             double* __restrict__ sums,
                             double* __restrict__ sumsq, int n) {
    __shared__ double la[256];
    __shared__ double lb[256];
    int tid = threadIdx.x;
    int t = tid & 31;
    int row = tid >> 5;  // 0..7
    double a = 0.0, b = 0.0;
    for (int v = blockIdx.x * 8 + row; v < n; v += gridDim.x * 8) {
        float x = s[(size_t)v * 32 + t];
        a += (double)x;
        b += (double)x * (double)x;
    }
    la[tid] = a; lb[tid] = b;
    __syncthreads();
    for (int off = 128; off >= 32; off >>= 1) {
        if (tid < off) { la[tid] += la[tid + off]; lb[tid] += lb[tid + off]; }
        __syncthreads();
    }
    if (tid < 32) {
        atomicAdd(&sums[t], la[tid]);
        atomicAdd(&sumsq[t], lb[tid]);
    }
}

// ---------------------------------------------------------------------------
// Finalize BN: scale = gamma * rsqrt(var + eps), shift = beta - mu*scale
// ---------------------------------------------------------------------------
__global__ void finalize_kernel(const double* __restrict__ sums,
                                const double* __restrict__ sumsq,
                                const float* __restrict__ gamma,
                                const float* __restrict__ beta,
                                float* __restrict__ scale,
                                float* __restrict__ shift, int n) {
    int t = threadIdx.x;
    if (t < 32) {
        double mu = sums[t] / (double)n;
        double var = sumsq[t] / (double)n - mu * mu;
        double sc = (double)gamma[t] / sqrt(var + 1e-3);
        scale[t] = (float)sc;
        shift[t] = (float)((double)beta[t] - mu * sc);
    }
}

// ---------------------------------------------------------------------------
// sig2 = relu(scale*s + shift)   (branch 1 epilogue -> conv2 input)
// ---------------------------------------------------------------------------
__global__ void affine_relu_kernel(const float* __restrict__ s,
                                   const float* __restrict__ scale,
                                   const float* __restrict__ shift,
                                   float* __restrict__ o, int n4) {
    int e = blockIdx.x * blockDim.x + threadIdx.x;
    if (e >= n4) return;
    int t0 = (e & 7) * 4;
    float4 x = ((const float4*)s)[e];
    float4 y;
    y.x = fmaxf(fmaf(scale[t0 + 0], x.x, shift[t0 + 0]), 0.f);
    y.y = fmaxf(fmaf(scale[t0 + 1], x.y, shift[t0 + 1]), 0.f);
    y.z = fmaxf(fmaf(scale[t0 + 2], x.z, shift[t0 + 2]), 0.f);
    y.w = fmaxf(fmaf(scale[t0 + 3], x.w, shift[t0 + 3]), 0.f);
    ((float4*)o)[e] = y;
}

// ---------------------------------------------------------------------------
// out = relu(scale*s + shift + signal)   (final residual epilogue)
// ---------------------------------------------------------------------------
__global__ void final_kernel(const float* __restrict__ s,
                             const float* __restrict__ scale,
                             const float* __restrict__ shift,
                             const float* __restrict__ sig,
                             float* __restrict__ o, int n4) {
    int e = blockIdx.x * blockDim.x + threadIdx.x;
    if (e >= n4) return;
    int t0 = (e & 7) * 4;
    float4 x = ((const float4*)s)[e];
    float4 z = ((const float4*)sig)[e];
    float4 y;
    y.x = fmaxf(fmaf(scale[t0 + 0], x.x, shift[t0 + 0]) + z.x, 0.f);
    y.y = fmaxf(fmaf(scale[t0 + 1], x.y, shift[t0 + 1]) + z.y, 0.f);
    y.z = fmaxf(fmaf(scale[t0 + 2], x.z, shift[t0 + 2]) + z.z, 0.f);
    y.w = fmaxf(fmaf(scale[t0 + 3], x.w, shift[t0 + 3]) + z.w, 0.f);
    ((float4*)o)[e] = y;
}

__global__ void zero_stats_kernel(double* __restrict__ d, float* __restrict__ f) {
    int t = threadIdx.x;
    if (t < 128) d[t] = 0.0;
    if (t < 128) f[t] = 0.f;
}

// ---------------------------------------------------------------------------
extern "C" void kernel_launch(void* const* d_in, const int* in_sizes, int n_in,
                              void* d_out, int out_size, void* d_ws, size_t ws_size,
                              hipStream_t stream) {
    const float* signal = (const float*)d_in[0];
    const int* bc_idx   = (const int*)d_in[1];
    const float* bc_w   = (const float*)d_in[2];
    const float* W1     = (const float*)d_in[3];
    const float* b1     = (const float*)d_in[4];
    const float* g1     = (const float*)d_in[5];
    const float* be1    = (const float*)d_in[6];
    const float* W2     = (const float*)d_in[7];
    const float* b2     = (const float*)d_in[8];
    const float* g2     = (const float*)d_in[9];
    const float* be2    = (const float*)d_in[10];
    float* out = (float*)d_out;

    const int N = in_sizes[0] / 32;  // 80000

    char* ws = (char*)d_ws;
    double* sums1  = (double*)ws;         // 32
    double* sumsq1 = sums1 + 32;
    double* sums2  = sums1 + 64;
    double* sumsq2 = sums1 + 96;
    float* scale1 = (float*)(ws + 1024);
    float* shift1 = scale1 + 32;
    float* scale2 = scale1 + 64;
    float* shift2 = scale1 + 96;
    float* Ws1 = (float*)(ws + 4096);                 // 40960 floats = 160 KB
    float* Ws2 = Ws1 + RR * DD * TT * 8;
    float* s1  = Ws2 + RR * DD * TT * 8;
    float* sg2 = s1 + (size_t)N * 32;
    float* s2  = sg2 + (size_t)N * 32;

    int nBlocks = (N + 127) / 128;             // 625
    int wBlocks = (TT * RR * DD + 255) / 256;  // 20

    zero_stats_kernel<<<1, 128, 0, stream>>>((double*)ws, (float*)(ws + 1024));
    wdft_kernel<<<wBlocks, 256, 0, stream>>>(W1, Ws1);
    wdft_kernel<<<wBlocks, 256, 0, stream>>>(W2, Ws2);

    // ---- branch 1: fused gather+DFT+spectral-conv+pool ----
    fused_conv_kernel<<<nBlocks, 256, 0, stream>>>(signal, bc_idx, bc_w, Ws1, b1, s1, N);
    stats_kernel<<<64, 256, 0, stream>>>(s1, sums1, sumsq1, N);
    finalize_kernel<<<1, 32, 0, stream>>>(sums1, sumsq1, g1, be1, scale1, shift1, N);
    affine_relu_kernel<<<(N * 8 + 255) / 256, 256, 0, stream>>>(s1, scale1, shift1, sg2, N * 8);

    // ---- branch 2 ----
    fused_conv_kernel<<<nBlocks, 256, 0, stream>>>(sg2, bc_idx, bc_w, Ws2, b2, s2, N);
    stats_kernel<<<64, 256, 0, stream>>>(s2, sums2, sumsq2, N);
    finalize_kernel<<<1, 32, 0, stream>>>(sums2, sumsq2, g2, be2, scale2, shift2, N);

    // ---- residual + relu ----
    final_kernel<<<(N * 8 + 255) / 256, 256, 0, stream>>>(s2, scale2, shift2, signal, out, N * 8);
}

// Round 8
// 808.726 us; speedup vs baseline: 2.9994x; 2.9994x over previous
//
#include <hip/hip_runtime.h>
#include <math.h>

// Problem constants (N=80000, Rr=5, A=8, D=32, T=32, K=8 rotations, ROT_DELTA=1)
#define RR 5
#define AA 8
#define DD 32
#define TT 32
#define KK 8

#define RT2 0.70710678118654752f

typedef float v2f __attribute__((ext_vector_type(2)));
typedef float v4f __attribute__((ext_vector_type(4)));

static __device__ __forceinline__ v2f pkfma(v2f a, v2f b, v2f c) {
#if __has_builtin(__builtin_elementwise_fma)
    return __builtin_elementwise_fma(a, b, c);
#else
    v2f r; r.x = fmaf(a.x, b.x, c.x); r.y = fmaf(a.y, b.y, c.y); return r;
#endif
}

// ---------------------------------------------------------------------------
// W spectral precompute.  Layout = exactly the per-(r,h) LDS slice the conv
// kernel stages with a dense identity copy:
//   Ws[(r*2+h)*4096 + fh*2048 + dl*128 + t*4 + f']
// where d = h*16 + dl, f = fh*4 + f',
// f-pack = [F0,F4,R1,I1 | R2,I2,R3,I3].  One thread per (t,r,d) = 5120.
// ---------------------------------------------------------------------------
__global__ void wdft_kernel(const float* __restrict__ W, float* __restrict__ Ws) {
    int idx = blockIdx.x * 256 + threadIdx.x;
    if (idx >= TT * RR * DD) return;
    int d = idx & 31;
    int tr = idx >> 5;      // t*5+r
    int t = tr / 5;
    int r = tr - t * 5;
    float xa[8];
    #pragma unroll
    for (int a = 0; a < 8; ++a) xa[a] = W[(tr * 8 + a) * 32 + d];
    float s0 = xa[0] + xa[4], d0 = xa[0] - xa[4];
    float s1 = xa[1] + xa[5], d1 = xa[1] - xa[5];
    float s2 = xa[2] + xa[6], d2 = xa[2] - xa[6];
    float s3 = xa[3] + xa[7], d3 = xa[3] - xa[7];
    float s02 = s0 + s2, s13 = s1 + s3;
    float F0 = s02 + s13, F4 = s02 - s13;
    float R2 = s0 - s2, I2 = s3 - s1;
    float u = RT2 * (d1 - d3), v = RT2 * (d1 + d3);
    float R1 = d0 + u, R3 = d0 - u;
    float I1 = -d2 - v, I3 = d2 - v;
    int h = d >> 4;
    int dl = d & 15;
    float* o0 = &Ws[(size_t)(r * 2 + h) * 4096 + dl * 128 + t * 4];
    float* o1 = o0 + 2048;
    o0[0] = F0; o0[1] = F4; o0[2] = R1; o0[3] = I1;
    o1[0] = R2; o1[1] = I2; o1[2] = R3; o1[3] = I3;
}

// ---------------------------------------------------------------------------
// Fused kernel: gather + barycentric interp (+ optional BN-affine+relu of the
// gathered signal, for branch 2) + forward DFT8 + spectral GEMM (vs conj W)
// + IDFT8 + bias + angular max pool.
//
// Block = 256 threads (4 waves), 64 v/block (1250 blocks), 3 blocks/CU
// (LDS 50,176 B): 12 waves/CU for LDS/VALU cross-wave overlap.
// d processed in two 16-d halves per r; per half: stage Wl (dense identity
// copy, conflict-free) + gather half-spectra -> Is, one barrier, GEMM.
// GEMM lane tile = 2 v x 4 t; v = wv*16 + vg + 8*vv (vg stride = 132 floats
// = 4 banks: Is reads conflict-free); Wl[fh*2048 + dl*128 + t*4] (tg stride
// 4 banks: conflict-free).  Norm reduce wave-local (shfl over tg bits).
// ---------------------------------------------------------------------------
template <bool AFFINE>
__global__ __launch_bounds__(256, 3)
void fused_conv_kernel(const float* __restrict__ sig,
                       const int* __restrict__ bc_idx,
                       const float* __restrict__ bc_w,
                       const float* __restrict__ Wsg,
                       const float* __restrict__ bias,
                       float* __restrict__ s_out,
                       const float* __restrict__ scaleIn,
                       const float* __restrict__ shiftIn,
                       int N) {
    __shared__ float Is[64 * 132];   // 33,792 B half-spectra, v-stride 132
    __shared__ float Wl[4096];       // 16,384 B W slice for (r,h)

    int tid = threadIdx.x;
    int vBase = blockIdx.x * 64;
    int lane = tid & 63;
    int wv = tid >> 6;

    // GEMM lane roles
    int vg = lane & 7;
    int tg = lane >> 3;              // 0..7

    // gather lane roles (float2 over d within a 16-d half)
    int d2 = tid & 7;                // floats 2*d2, 2*d2+1 of the half
    int g = tid >> 3;                // 0..31 (vertex; 2 passes for 64)

    // branch-2 fused BN affine coefficients for this lane's d positions
    v2f scH[2], shH[2];
    if (AFFINE) {
        #pragma unroll
        for (int h = 0; h < 2; ++h) {
            scH[h] = *(const v2f*)&scaleIn[h * 16 + 2 * d2];
            shH[h] = *(const v2f*)&shiftIn[h * 16 + 2 * d2];
        }
    }

    // spectral accumulators [vv][j]: A0=(C0,C4) A1=(R1,I1) A2=(R2,I2) A3=(R3,I3)
    v2f A0[2][4], A1[2][4], A2[2][4], A3[2][4];
    #pragma unroll
    for (int vv = 0; vv < 2; ++vv)
        #pragma unroll
        for (int j = 0; j < 4; ++j) {
            A0[vv][j] = (v2f){0.f, 0.f}; A1[vv][j] = (v2f){0.f, 0.f};
            A2[vv][j] = (v2f){0.f, 0.f}; A3[vv][j] = (v2f){0.f, 0.f};
        }

    const v2f rt2 = {RT2, RT2};
    int vrow0 = (wv * 16 + vg) * 132;
    int vrow1 = vrow0 + 8 * 132;

    for (int r = 0; r < RR; ++r) {
        #pragma unroll
        for (int h = 0; h < 2; ++h) {
            __syncthreads();  // prev GEMM done reading Is & Wl

            // ---- stage Wl for (r,h): dense identity copy (conflict-free) ----
            {
                const v4f* src = (const v4f*)(Wsg + (size_t)(r * 2 + h) * 4096);
                #pragma unroll
                for (int k = 0; k < 4; ++k) {
                    v4f val = src[k * 256 + tid];
                    *(v4f*)&Wl[k * 1024 + tid * 4] = val;
                }
            }

            // ---- gather + interp (+affine/relu) + forward DFT8 -> Is ----
            #pragma unroll
            for (int pass = 0; pass < 2; ++pass) {
                int vv = g + 32 * pass;          // 0..63
                int vgl = vBase + vv;
                int vgc = (vgl < N) ? vgl : (N - 1);
                int base = (vgc * 40 + r * 8) * 3;
                v2f xa[8];
                #pragma unroll
                for (int a = 0; a < 8; ++a) {
                    int i0 = bc_idx[base + a * 3 + 0];
                    int i1 = bc_idx[base + a * 3 + 1];
                    int i2 = bc_idx[base + a * 3 + 2];
                    float w0 = bc_w[base + a * 3 + 0];
                    float w1 = bc_w[base + a * 3 + 1];
                    float w2 = bc_w[base + a * 3 + 2];
                    v2f r0 = *(const v2f*)&sig[(size_t)i0 * 32 + h * 16 + 2 * d2];
                    v2f r1 = *(const v2f*)&sig[(size_t)i1 * 32 + h * 16 + 2 * d2];
                    v2f r2 = *(const v2f*)&sig[(size_t)i2 * 32 + h * 16 + 2 * d2];
                    if (AFFINE) {
                        r0.x = fmaxf(fmaf(scH[h].x, r0.x, shH[h].x), 0.f);
                        r0.y = fmaxf(fmaf(scH[h].y, r0.y, shH[h].y), 0.f);
                        r1.x = fmaxf(fmaf(scH[h].x, r1.x, shH[h].x), 0.f);
                        r1.y = fmaxf(fmaf(scH[h].y, r1.y, shH[h].y), 0.f);
                        r2.x = fmaxf(fmaf(scH[h].x, r2.x, shH[h].x), 0.f);
                        r2.y = fmaxf(fmaf(scH[h].y, r2.y, shH[h].y), 0.f);
                    }
                    v2f w0v = {w0, w0};
                    v2f w1v = {w1, w1};
                    v2f w2v = {w2, w2};
                    xa[a] = pkfma(w2v, r2, pkfma(w1v, r1, w0v * r0));
                }
                // DFT8 (2 d-channels packed)
                v2f s0 = xa[0] + xa[4], dd0 = xa[0] - xa[4];
                v2f s1 = xa[1] + xa[5], dd1 = xa[1] - xa[5];
                v2f s2 = xa[2] + xa[6], dd2 = xa[2] - xa[6];
                v2f s3 = xa[3] + xa[7], dd3 = xa[3] - xa[7];
                v2f s02 = s0 + s2, s13 = s1 + s3;
                v2f F0 = s02 + s13, F4 = s02 - s13;
                v2f R2 = s0 - s2, I2 = s3 - s1;
                v2f u = rt2 * (dd1 - dd3), vvv = rt2 * (dd1 + dd3);
                v2f R1 = dd0 + u, R3 = dd0 - u;
                v2f I1 = -dd2 - vvv, I3 = dd2 - vvv;
                // transpose to per-d spectra (4 x b128, dense quads)
                float* ob = &Is[vv * 132 + d2 * 16];
                *(v4f*)&ob[0]  = (v4f){F0.x, F4.x, R1.x, I1.x};
                *(v4f*)&ob[4]  = (v4f){R2.x, I2.x, R3.x, I3.x};
                *(v4f*)&ob[8]  = (v4f){F0.y, F4.y, R1.y, I1.y};
                *(v4f*)&ob[12] = (v4f){R2.y, I2.y, R3.y, I3.y};
            }
            __syncthreads();  // Is + Wl visible

            // ---- spectral GEMM over this half's 16 d ----
            #pragma unroll 2
            for (int dl = 0; dl < 16; ++dl) {
                v4f p0a = *(const v4f*)&Is[vrow0 + dl * 8];
                v4f p1a = *(const v4f*)&Is[vrow0 + dl * 8 + 4];
                v4f p0b = *(const v4f*)&Is[vrow1 + dl * 8];
                v4f p1b = *(const v4f*)&Is[vrow1 + dl * 8 + 4];
                v2f x1a = p0a.zw, x1na = {p0a.w, -p0a.z};
                v2f x2a = p1a.xy, x2na = {p1a.y, -p1a.x};
                v2f x3a = p1a.zw, x3na = {p1a.w, -p1a.z};
                v2f x1b = p0b.zw, x1nb = {p0b.w, -p0b.z};
                v2f x2b = p1b.xy, x2nb = {p1b.y, -p1b.x};
                v2f x3b = p1b.zw, x3nb = {p1b.w, -p1b.z};
                #pragma unroll
                for (int j = 0; j < 4; ++j) {
                    v4f q0 = *(const v4f*)&Wl[dl * 128 + (tg + 8 * j) * 4];
                    v4f q1 = *(const v4f*)&Wl[2048 + dl * 128 + (tg + 8 * j) * 4];
                    v2f w2v = {q0.z, q0.z}, w3v = {q0.w, q0.w};
                    v2f w4v = {q1.x, q1.x}, w5v = {q1.y, q1.y};
                    v2f w6v = {q1.z, q1.z}, w7v = {q1.w, q1.w};
                    A0[0][j] = pkfma(p0a.xy, q0.xy, A0[0][j]);
                    A1[0][j] = pkfma(x1a, w2v, A1[0][j]);
                    A1[0][j] = pkfma(x1na, w3v, A1[0][j]);
                    A2[0][j] = pkfma(x2a, w4v, A2[0][j]);
                    A2[0][j] = pkfma(x2na, w5v, A2[0][j]);
                    A3[0][j] = pkfma(x3a, w6v, A3[0][j]);
                    A3[0][j] = pkfma(x3na, w7v, A3[0][j]);
                    A0[1][j] = pkfma(p0b.xy, q0.xy, A0[1][j]);
                    A1[1][j] = pkfma(x1b, w2v, A1[1][j]);
                    A1[1][j] = pkfma(x1nb, w3v, A1[1][j]);
                    A2[1][j] = pkfma(x2b, w4v, A2[1][j]);
                    A2[1][j] = pkfma(x2nb, w5v, A2[1][j]);
                    A3[1][j] = pkfma(x3b, w6v, A3[1][j]);
                    A3[1][j] = pkfma(x3nb, w7v, A3[1][j]);
                }
            }
        }
    }

    // ---- epilogue per vv: IDFT8 + bias, wave-local pool, store ----
    float bj[4];
    #pragma unroll
    for (int j = 0; j < 4; ++j) bj[j] = bias[tg + 8 * j];

    #pragma unroll
    for (int vv = 0; vv < 2; ++vv) {
        float outk[8][4];
        #pragma unroll
        for (int j = 0; j < 4; ++j) {
            float C0 = A0[vv][j].x, C4 = A0[vv][j].y;
            float R1 = A1[vv][j].x, I1 = A1[vv][j].y;
            float R2 = A2[vv][j].x, I2 = A2[vv][j].y;
            float R3 = A3[vv][j].x, I3 = A3[vv][j].y;
            float e = 0.125f * (C0 + C4), o = 0.125f * (C0 - C4);
            float p = 0.25f * (R1 + R3), q = 0.25f * R2, s = 0.25f * (I1 - I3);
            float a_ = 0.25f * RT2 * (R1 - R3);
            float b_ = 0.25f * RT2 * (I1 + I3);
            float c_ = 0.25f * I2;
            float bb = bj[j];
            outk[0][j] = e + p + q + bb;
            outk[1][j] = o + a_ - b_ - c_ + bb;
            outk[2][j] = e - s - q + bb;
            outk[3][j] = o - a_ - b_ + c_ + bb;
            outk[4][j] = e - p + q + bb;
            outk[5][j] = o - a_ + b_ - c_ + bb;
            outk[6][j] = e + s - q + bb;
            outk[7][j] = o + a_ + b_ + c_ + bb;
        }
        float norms[8];
        #pragma unroll
        for (int k = 0; k < 8; ++k) {
            float nl = 0.f;
            #pragma unroll
            for (int j = 0; j < 4; ++j)
                nl = fmaf(outk[k][j], outk[k][j], nl);
            nl += __shfl_xor(nl, 8);
            nl += __shfl_xor(nl, 16);
            nl += __shfl_xor(nl, 32);
            norms[k] = nl;
        }
        float best = -1.f;
        int bk = 0;
        #pragma unroll
        for (int k = 0; k < 8; ++k) {
            float n = sqrtf(norms[k]);
            if (n > best) { best = n; bk = k; }
        }
        int vOut = vBase + wv * 16 + vg + 8 * vv;
        if (vOut < N) {
            float sel[4];
            #pragma unroll
            for (int j = 0; j < 4; ++j) sel[j] = 0.f;
            #pragma unroll
            for (int k = 0; k < 8; ++k) {
                if (k == bk) {
                    #pragma unroll
                    for (int j = 0; j < 4; ++j) sel[j] = outk[k][j];
                }
            }
            float* o = s_out + (size_t)vOut * 32 + tg;
            o[0]  = sel[0];
            o[8]  = sel[1];
            o[16] = sel[2];
            o[24] = sel[3];
        }
    }
}

// ---------------------------------------------------------------------------
// Stats: per-column (t) sum and sumsq over N rows, fp64 accumulation.
// ---------------------------------------------------------------------------
__global__ void stats_kernel(const float* __restrict__ s,
                             double* __restrict__ sums,
                             double* __restrict__ sumsq, int n) {
    __shared__ double la[256];
    __shared__ double lb[256];
    int tid = threadIdx.x;
    int t = tid & 31;
    int row = tid >> 5;  // 0..7
    double a = 0.0, b = 0.0;
    for (int v = blockIdx.x * 8 + row; v < n; v += gridDim.x * 8) {
        float x = s[(size_t)v * 32 + t];
        a += (double)x;
        b += (double)x * (double)x;
    }
    la[tid] = a; lb[tid] = b;
    __syncthreads();
    for (int off = 128; off >= 32; off >>= 1) {
        if (tid < off) { la[tid] += la[tid + off]; lb[tid] += lb[tid + off]; }
        __syncthreads();
    }
    if (tid < 32) {
        atomicAdd(&sums[t], la[tid]);
        atomicAdd(&sumsq[t], lb[tid]);
    }
}

// ---------------------------------------------------------------------------
// Finalize BN: scale = gamma * rsqrt(var + eps), shift = beta - mu*scale
// ---------------------------------------------------------------------------
__global__ void finalize_kernel(const double* __restrict__ sums,
                                const double* __restrict__ sumsq,
                                const float* __restrict__ gamma,
                                const float* __restrict__ beta,
                                float* __restrict__ scale,
                                float* __restrict__ shift, int n) {
    int t = threadIdx.x;
    if (t < 32) {
        double mu = sums[t] / (double)n;
        double var = sumsq[t] / (double)n - mu * mu;
        double sc = (double)gamma[t] / sqrt(var + 1e-3);
        scale[t] = (float)sc;
        shift[t] = (float)((double)beta[t] - mu * sc);
    }
}

// ---------------------------------------------------------------------------
// out = relu(scale*s + shift + signal)   (final residual epilogue)
// ---------------------------------------------------------------------------
__global__ void final_kernel(const float* __restrict__ s,
                             const float* __restrict__ scale,
                             const float* __restrict__ shift,
                             const float* __restrict__ sig,
                             float* __restrict__ o, int n4) {
    int e = blockIdx.x * blockDim.x + threadIdx.x;
    if (e >= n4) return;
    int t0 = (e & 7) * 4;
    float4 x = ((const float4*)s)[e];
    float4 z = ((const float4*)sig)[e];
    float4 y;
    y.x = fmaxf(fmaf(scale[t0 + 0], x.x, shift[t0 + 0]) + z.x, 0.f);
    y.y = fmaxf(fmaf(scale[t0 + 1], x.y, shift[t0 + 1]) + z.y, 0.f);
    y.z = fmaxf(fmaf(scale[t0 + 2], x.z, shift[t0 + 2]) + z.z, 0.f);
    y.w = fmaxf(fmaf(scale[t0 + 3], x.w, shift[t0 + 3]) + z.w, 0.f);
    ((float4*)o)[e] = y;
}

__global__ void zero_stats_kernel(double* __restrict__ d, float* __restrict__ f) {
    int t = threadIdx.x;
    if (t < 128) d[t] = 0.0;
    if (t < 128) f[t] = 0.f;
}

// ---------------------------------------------------------------------------
extern "C" void kernel_launch(void* const* d_in, const int* in_sizes, int n_in,
                              void* d_out, int out_size, void* d_ws, size_t ws_size,
                              hipStream_t stream) {
    const float* signal = (const float*)d_in[0];
    const int* bc_idx   = (const int*)d_in[1];
    const float* bc_w   = (const float*)d_in[2];
    const float* W1     = (const float*)d_in[3];
    const float* b1     = (const float*)d_in[4];
    const float* g1     = (const float*)d_in[5];
    const float* be1    = (const float*)d_in[6];
    const float* W2     = (const float*)d_in[7];
    const float* b2     = (const float*)d_in[8];
    const float* g2     = (const float*)d_in[9];
    const float* be2    = (const float*)d_in[10];
    float* out = (float*)d_out;

    const int N = in_sizes[0] / 32;  // 80000

    char* ws = (char*)d_ws;
    double* sums1  = (double*)ws;         // 32
    double* sumsq1 = sums1 + 32;
    double* sums2  = sums1 + 64;
    double* sumsq2 = sums1 + 96;
    float* scale1 = (float*)(ws + 1024);
    float* shift1 = scale1 + 32;
    float* scale2 = scale1 + 64;
    float* shift2 = scale1 + 96;
    float* Ws1 = (float*)(ws + 4096);                 // 40960 floats = 160 KB
    float* Ws2 = Ws1 + RR * DD * TT * 8;
    float* s1  = Ws2 + RR * DD * TT * 8;
    float* s2  = s1 + (size_t)N * 32;

    int nBlocks = (N + 63) / 64;               // 1250
    int wBlocks = (TT * RR * DD + 255) / 256;  // 20

    zero_stats_kernel<<<1, 128, 0, stream>>>((double*)ws, (float*)(ws + 1024));
    wdft_kernel<<<wBlocks, 256, 0, stream>>>(W1, Ws1);
    wdft_kernel<<<wBlocks, 256, 0, stream>>>(W2, Ws2);

    // ---- branch 1: fused gather+DFT+spectral-conv+pool ----
    fused_conv_kernel<false><<<nBlocks, 256, 0, stream>>>(
        signal, bc_idx, bc_w, Ws1, b1, s1, nullptr, nullptr, N);
    stats_kernel<<<64, 256, 0, stream>>>(s1, sums1, sumsq1, N);
    finalize_kernel<<<1, 32, 0, stream>>>(sums1, sumsq1, g1, be1, scale1, shift1, N);

    // ---- branch 2 (BN-affine+relu of s1 fused into the gather) ----
    fused_conv_kernel<true><<<nBlocks, 256, 0, stream>>>(
        s1, bc_idx, bc_w, Ws2, b2, s2, scale1, shift1, N);
    stats_kernel<<<64, 256, 0, stream>>>(s2, sums2, sumsq2, N);
    finalize_kernel<<<1, 32, 0, stream>>>(sums2, sumsq2, g2, be2, scale2, shift2, N);

    // ---- residual + relu ----
    final_kernel<<<(N * 8 + 255) / 256, 256, 0, stream>>>(s2, scale2, shift2, signal, out, N * 8);
}